// Round 6
// baseline (349.741 us; speedup 1.0000x reference)
//
#include <hip/hip_runtime.h>
#include <hip/hip_bf16.h>
#include <math.h>

#define BB 8
#define NN 2048
#define CC 128
#define DD 128
#define NGRP ((NN / 64) * BB)     // gat groups for split-counter

typedef __attribute__((ext_vector_type(8))) short short8;
typedef __attribute__((ext_vector_type(4))) float f32x4;

static __device__ __forceinline__ unsigned short f2bf(float f) {
    __hip_bfloat16 h = __float2bfloat16(f);
    return *reinterpret_cast<unsigned short*>(&h);
}
static __device__ __forceinline__ float bf2f(unsigned short u) {
    __hip_bfloat16 h = *reinterpret_cast<__hip_bfloat16*>(&u);
    return __bfloat162float(h);
}

// ---------------- Kernel P: pack adj bitmask + split W hi/lo + zero counters
#define PACK_BLOCKS (NN * NN / 256)          // 16384
#define WSPL_BLOCKS (DD * CC / 256)          // 64
__global__ __launch_bounds__(256) void prep_kernel(
    const int* __restrict__ adj, unsigned int* __restrict__ padj,
    const float* __restrict__ W,
    unsigned short* __restrict__ Whi, unsigned short* __restrict__ Wlo,
    int* __restrict__ cnt)
{
    const int bx  = blockIdx.x;
    const int tid = threadIdx.x;
    if (bx < PACK_BLOCKS) {
        const int idx  = bx * 256 + tid;      // element of adj
        const int i    = idx >> 11;
        const int j    = idx & 2047;
        const int lane = tid & 63;
        int ad = adj[(size_t)i * NN + j];
        unsigned long long m = __ballot(ad > 0);
        if (lane == 0)  padj[i * 64 + (j >> 5)] = (unsigned int)m;
        if (lane == 32) padj[i * 64 + (j >> 5)] = (unsigned int)(m >> 32);
    } else if (bx < PACK_BLOCKS + WSPL_BLOCKS) {
        const int g = (bx - PACK_BLOCKS) * 256 + tid;
        float w = W[g];
        unsigned short h = f2bf(w);
        Whi[g] = h;
        Wlo[g] = f2bf(w - bf2f(h));
    } else {
        if (tid < NGRP) cnt[tid] = 0;
    }
}

// ---------------- Kernel A: Wh = x @ W^T via compensated MFMA.
// Writes WhbT bf16 [b][d][n], f1 (raw), E2=exp(f2), G2=exp(0.2 f2).
__global__ __launch_bounds__(256) void wh_kernel(
    const float* __restrict__ x,
    const unsigned short* __restrict__ Whi, const unsigned short* __restrict__ Wlo,
    const float* __restrict__ a,
    unsigned short* __restrict__ WhbT,
    float* __restrict__ f1, float* __restrict__ E2g, float* __restrict__ G2g)
{
    const int tid  = threadIdx.x;
    const int b    = blockIdx.y;
    const int n0   = blockIdx.x * 64;
    const int w    = tid >> 6;
    const int lane = tid & 63;
    const int fr   = lane & 15, fk = lane >> 4;
    const int n    = n0 + w * 16 + fr;

    short8 bh[4], bl[4];
    const float* xrow = &x[((size_t)(b * NN) + n) * CC];
    #pragma unroll
    for (int ks = 0; ks < 4; ++ks) {
        float xv[8];
        *(float4*)&xv[0] = *(const float4*)&xrow[(ks * 4 + fk) * 8];
        *(float4*)&xv[4] = *(const float4*)&xrow[(ks * 4 + fk) * 8 + 4];
        #pragma unroll
        for (int e = 0; e < 8; ++e) {
            unsigned short h = f2bf(xv[e]);
            bh[ks][e] = (short)h;
            bl[ks][e] = (short)f2bf(xv[e] - bf2f(h));
        }
    }

    f32x4 acc[8];
    #pragma unroll
    for (int dt = 0; dt < 8; ++dt) acc[dt] = (f32x4){0.f, 0.f, 0.f, 0.f};

    #pragma unroll
    for (int dt = 0; dt < 8; ++dt) {
        #pragma unroll
        for (int ks = 0; ks < 4; ++ks) {
            const int off = (dt * 16 + fr) * CC + (ks * 4 + fk) * 8;
            short8 aH = *(const short8*)&Whi[off];
            short8 aL = *(const short8*)&Wlo[off];
            acc[dt] = __builtin_amdgcn_mfma_f32_16x16x32_bf16(aH, bh[ks], acc[dt], 0, 0, 0);
            acc[dt] = __builtin_amdgcn_mfma_f32_16x16x32_bf16(aH, bl[ks], acc[dt], 0, 0, 0);
            acc[dt] = __builtin_amdgcn_mfma_f32_16x16x32_bf16(aL, bh[ks], acc[dt], 0, 0, 0);
        }
    }

    float p1 = 0.f, p2 = 0.f;
    #pragma unroll
    for (int dt = 0; dt < 8; ++dt) {
        #pragma unroll
        for (int r = 0; r < 4; ++r) {
            const int d = dt * 16 + fk * 4 + r;
            p1 += acc[dt][r] * a[d];
            p2 += acc[dt][r] * a[DD + d];
        }
    }
    p1 += __shfl_xor(p1, 16); p1 += __shfl_xor(p1, 32);
    p2 += __shfl_xor(p2, 16); p2 += __shfl_xor(p2, 32);
    if (fk == 0) {
        f1[b * NN + n]  = p1;
        E2g[b * NN + n] = __expf(p2);
        G2g[b * NN + n] = __expf(0.2f * p2);
    }

    #pragma unroll
    for (int dt = 0; dt < 8; ++dt) {
        #pragma unroll
        for (int r = 0; r < 4; ++r) {
            const int d = dt * 16 + fk * 4 + r;
            WhbT[((size_t)(b * 128 + d)) * NN + n] = f2bf(acc[dt][r]);
        }
    }
}

// ---------------- Kernel C: MFMA attention, 64 i-rows x 128 d, 8 waves.
// P weight = max(E1*E2, G1*G2) == exp(leaky_relu(f1+f2)) (exact identity).
// !DIRECT: split-j partials; last block per (b,i0) group fuses the reduce.
template<int S, bool DIRECT>
__global__ __launch_bounds__(512) void gat_kernel(
    const unsigned short* __restrict__ WhbT,   // [b][128 d][2048 n] bf16
    const unsigned int* __restrict__ padj,     // [2048][64] bitmask
    const float* __restrict__ f1,
    const float* __restrict__ E2g, const float* __restrict__ G2g,
    float* __restrict__ out,
    float* __restrict__ pPV, float* __restrict__ pS, int* __restrict__ cnt)
{
    constexpr int JS = NN / S;
    constexpr int NC = JS / 64;
    __shared__ __align__(16) unsigned short Bs[128 * 64];  // 16 KB
    __shared__ __align__(16) unsigned short Ps[64 * 64];   // 8 KB
    __shared__ float E2s[JS];
    __shared__ float G2s[JS];
    __shared__ float Srow[64];
    __shared__ float Sred[64];
    __shared__ int lastFlag;

    const int tid   = threadIdx.x;
    const int i0    = blockIdx.x * 64;
    const int split = blockIdx.y;
    const int b     = blockIdx.z;
    const int jBeg  = split * JS;

    #pragma unroll
    for (int k = 0; k < JS / 512; ++k) {
        E2s[tid + 512 * k] = E2g[b * NN + jBeg + tid + 512 * k];
        G2s[tid + 512 * k] = G2g[b * NN + jBeg + tid + 512 * k];
    }

    // P role: row = tid>>3 (64 rows), 8 j-elems at pjb*8
    const int prow = tid >> 3;
    const int pjb  = tid & 7;
    const float f1r = f1[b * NN + i0 + prow];
    const float E1r = __expf(f1r);
    const float G1r = __expf(0.2f * f1r);
    const int psw = ((pjb ^ (prow & 7)) << 3);
    const unsigned int* padjRow = padj + (size_t)(i0 + prow) * 64 + (jBeg >> 5);

    // MFMA role: wave (wr,wc) in 2x4
    const int w    = tid >> 6;
    const int wr   = w >> 2, wc = w & 3;
    const int lane = tid & 63;
    const int fr   = lane & 15;
    const int fk   = lane >> 4;
    f32x4 acc00 = {0.f,0.f,0.f,0.f}, acc01 = {0.f,0.f,0.f,0.f};
    f32x4 acc10 = {0.f,0.f,0.f,0.f}, acc11 = {0.f,0.f,0.f,0.f};
    float s_part = 0.f;

    // B staging: 1024 x 16B loads, 2 per thread
    const size_t wbase = (size_t)b * 128 * NN;
    const int g0 = tid,       gd0 = g0 >> 3, gj0 = (g0 & 7) * 8;
    const int g1 = tid + 512, gd1 = g1 >> 3, gj1 = (g1 & 7) * 8;
    const int sw0 = gd0 * 64 + ((((g0) & 7) ^ (gd0 & 7)) << 3);
    const int sw1 = gd1 * 64 + ((((g1) & 7) ^ (gd1 & 7)) << 3);

    // prefetch chunk 0
    uint4 br0 = *(const uint4*)&WhbT[wbase + (size_t)gd0 * NN + jBeg + gj0];
    uint4 br1 = *(const uint4*)&WhbT[wbase + (size_t)gd1 * NN + jBeg + gj1];
    unsigned int pw = padjRow[pjb >> 2];

    __syncthreads();   // E2s/G2s ready

    for (int c = 0; c < NC; ++c) {
        // (B) P chunk: w = max(E1*E2, G1*G2), masked by bit
        float4 eA = *(const float4*)&E2s[c * 64 + pjb * 8];
        float4 eB = *(const float4*)&E2s[c * 64 + pjb * 8 + 4];
        float4 gA = *(const float4*)&G2s[c * 64 + pjb * 8];
        float4 gB = *(const float4*)&G2s[c * 64 + pjb * 8 + 4];
        float ev[8], gv[8];
        *(float4*)&ev[0] = eA; *(float4*)&ev[4] = eB;
        *(float4*)&gv[0] = gA; *(float4*)&gv[4] = gB;
        unsigned int pbits = (pw >> ((pjb & 3) << 3)) & 0xffu;
        unsigned short pks[8];
        float ssum = 0.f;
        #pragma unroll
        for (int e = 0; e < 8; ++e) {
            float m  = E1r * ev[e];
            float g  = G1r * gv[e];
            float wv = fmaxf(m, g);
            wv = ((pbits >> e) & 1u) ? wv : 0.f;
            unsigned short bw = f2bf(wv);
            pks[e] = bw;
            ssum += bf2f(bw);
        }
        s_part += ssum;

        if (c > 0) __syncthreads();   // prev MFMA done reading LDS
        // (C) LDS writes
        *(uint4*)&Bs[sw0] = br0;
        *(uint4*)&Bs[sw1] = br1;
        {
            uint4 pv;
            pv.x = (unsigned int)pks[0] | ((unsigned int)pks[1] << 16);
            pv.y = (unsigned int)pks[2] | ((unsigned int)pks[3] << 16);
            pv.z = (unsigned int)pks[4] | ((unsigned int)pks[5] << 16);
            pv.w = (unsigned int)pks[6] | ((unsigned int)pks[7] << 16);
            *(uint4*)&Ps[prow * 64 + psw] = pv;
        }
        // (A) prefetch next chunk
        if (c + 1 < NC) {
            const int j0n = jBeg + (c + 1) * 64;
            br0 = *(const uint4*)&WhbT[wbase + (size_t)gd0 * NN + j0n + gj0];
            br1 = *(const uint4*)&WhbT[wbase + (size_t)gd1 * NN + j0n + gj1];
            pw  = padjRow[(c + 1) * 2 + (pjb >> 2)];
        }
        __syncthreads();   // tiles ready
        // (D) MFMA
        __builtin_amdgcn_s_setprio(1);
        #pragma unroll
        for (int ks = 0; ks < 2; ++ks) {
            const int jbl = ks * 4 + fk;
            const int sb  = ((jbl ^ (fr & 7)) << 3);
            short8 aF0 = *(const short8*)&Ps[(wr * 32 + fr) * 64 + sb];
            short8 aF1 = *(const short8*)&Ps[(wr * 32 + 16 + fr) * 64 + sb];
            short8 bF0 = *(const short8*)&Bs[(wc * 32 + fr) * 64 + sb];
            short8 bF1 = *(const short8*)&Bs[(wc * 32 + 16 + fr) * 64 + sb];
            acc00 = __builtin_amdgcn_mfma_f32_16x16x32_bf16(aF0, bF0, acc00, 0, 0, 0);
            acc01 = __builtin_amdgcn_mfma_f32_16x16x32_bf16(aF0, bF1, acc01, 0, 0, 0);
            acc10 = __builtin_amdgcn_mfma_f32_16x16x32_bf16(aF1, bF0, acc10, 0, 0, 0);
            acc11 = __builtin_amdgcn_mfma_f32_16x16x32_bf16(aF1, bF1, acc11, 0, 0, 0);
        }
        __builtin_amdgcn_s_setprio(0);
    }

    // row-sum: 8 threads per row
    {
        float v = s_part;
        v += __shfl_xor(v, 1); v += __shfl_xor(v, 2); v += __shfl_xor(v, 4);
        if (pjb == 0) Srow[prow] = v;
    }
    __syncthreads();

    if (DIRECT) {
        if (tid < 64) Sred[tid] = 1.0f / Srow[tid];
        __syncthreads();
        #pragma unroll
        for (int it = 0; it < 2; ++it) {
            #pragma unroll
            for (int dt = 0; dt < 2; ++dt) {
                f32x4 av = (it == 0) ? (dt == 0 ? acc00 : acc01)
                                     : (dt == 0 ? acc10 : acc11);
                #pragma unroll
                for (int r = 0; r < 4; ++r) {
                    int i = wr * 32 + it * 16 + fk * 4 + r;
                    int d = wc * 32 + dt * 16 + fr;
                    float hv = av[r] * Sred[i];
                    hv = (hv > 0.f) ? hv : expm1f(hv);
                    out[((size_t)(b * NN) + i0 + i) * DD + d] = hv;
                }
            }
        }
        return;
    }

    // ---- split path: write partials
    if (tid < 64)
        pS[(size_t)(b * S + split) * NN + i0 + tid] = Srow[tid];
    #pragma unroll
    for (int it = 0; it < 2; ++it) {
        #pragma unroll
        for (int dt = 0; dt < 2; ++dt) {
            f32x4 av = (it == 0) ? (dt == 0 ? acc00 : acc01)
                                 : (dt == 0 ? acc10 : acc11);
            #pragma unroll
            for (int r = 0; r < 4; ++r) {
                int i = wr * 32 + it * 16 + fk * 4 + r;
                int d = wc * 32 + dt * 16 + fr;
                pPV[((size_t)(b * S + split) * NN + i0 + i) * DD + d] = av[r];
            }
        }
    }

    // ---- last-block-done fused reduce
    __threadfence();
    if (tid == 0) {
        int prev = atomicAdd(&cnt[b * (NN / 64) + blockIdx.x], 1);
        lastFlag = (prev == S - 1);
    }
    __syncthreads();
    if (!lastFlag) return;
    __threadfence();

    if (tid < 64) {
        float st = 0.f;
        #pragma unroll
        for (int s = 0; s < S; ++s)
            st += pS[(size_t)(b * S + s) * NN + i0 + tid];
        Sred[tid] = 1.0f / st;
    }
    __syncthreads();

    #pragma unroll
    for (int k = 0; k < 4; ++k) {
        const int e4  = tid + k * 512;       // float4 index within 64x128 tile
        const int row = e4 >> 5;
        const int d4  = (e4 & 31) * 4;
        float4 sum = make_float4(0.f, 0.f, 0.f, 0.f);
        #pragma unroll
        for (int s = 0; s < S; ++s) {
            const float4 v = *(const float4*)
                &pPV[((size_t)(b * S + s) * NN + i0 + row) * DD + d4];
            sum.x += v.x; sum.y += v.y; sum.z += v.z; sum.w += v.w;
        }
        const float inv = Sred[row];
        float4 h;
        h.x = sum.x * inv; h.y = sum.y * inv; h.z = sum.z * inv; h.w = sum.w * inv;
        h.x = (h.x > 0.f) ? h.x : expm1f(h.x);
        h.y = (h.y > 0.f) ? h.y : expm1f(h.y);
        h.z = (h.z > 0.f) ? h.z : expm1f(h.z);
        h.w = (h.w > 0.f) ? h.w : expm1f(h.w);
        *(float4*)&out[((size_t)(b * NN) + i0 + row) * DD + d4] = h;
    }
}

extern "C" void kernel_launch(void* const* d_in, const int* in_sizes, int n_in,
                              void* d_out, int out_size, void* d_ws, size_t ws_size,
                              hipStream_t stream) {
    const float* x   = (const float*)d_in[0];
    const int*   adj = (const int*)d_in[1];
    const float* W   = (const float*)d_in[2];
    const float* a   = (const float*)d_in[3];
    float* out = (float*)d_out;

    char* p = (char*)d_ws;
    unsigned short* WhbT = (unsigned short*)p; p += (size_t)BB * NN * DD * 2;  // 4 MB
    float* f1  = (float*)p; p += (size_t)BB * NN * 4;
    float* E2g = (float*)p; p += (size_t)BB * NN * 4;
    float* G2g = (float*)p; p += (size_t)BB * NN * 4;
    unsigned short* Whi = (unsigned short*)p; p += (size_t)DD * CC * 2;
    unsigned short* Wlo = (unsigned short*)p; p += (size_t)DD * CC * 2;
    unsigned int* padj  = (unsigned int*)p;   p += (size_t)NN * 64 * 4;        // 512 KB
    int* cnt = (int*)p; p += 1024;                                             // 256 ints, pad
    float* pPV = (float*)p;

    const size_t base_bytes = (size_t)(p - (char*)d_ws);
    const size_t per_split  = (size_t)BB * NN * DD * 4 + (size_t)BB * NN * 4;

    prep_kernel<<<PACK_BLOCKS + WSPL_BLOCKS + 1, 256, 0, stream>>>(
        adj, padj, W, Whi, Wlo, cnt);
    wh_kernel<<<dim3(NN / 64, BB), 256, 0, stream>>>(x, Whi, Wlo, a, WhbT, f1, E2g, G2g);

    if (ws_size >= base_bytes + 4 * per_split) {
        constexpr int S = 4;
        float* pS = pPV + (size_t)S * BB * NN * DD;
        gat_kernel<S, false><<<dim3(NN / 64, S, BB), 512, 0, stream>>>(
            WhbT, padj, f1, E2g, G2g, out, pPV, pS, cnt);
    } else {
        gat_kernel<1, true><<<dim3(NN / 64, 1, BB), 512, 0, stream>>>(
            WhbT, padj, f1, E2g, G2g, out, nullptr, nullptr, cnt);
    }
}

// Round 7
// 48.995 us; speedup vs baseline: 7.1383x; 7.1383x over previous
//
#include <hip/hip_runtime.h>
#include <hip/hip_bf16.h>
#include <math.h>

#define BB 8
#define NN 2048
#define CC 128
#define DD 128

typedef __attribute__((ext_vector_type(8))) short short8;
typedef __attribute__((ext_vector_type(4))) float f32x4;

static __device__ __forceinline__ unsigned short f2bf(float f) {
    __hip_bfloat16 h = __float2bfloat16(f);
    return *reinterpret_cast<unsigned short*>(&h);
}
static __device__ __forceinline__ float bf2f(unsigned short u) {
    __hip_bfloat16 h = *reinterpret_cast<__hip_bfloat16*>(&u);
    return __bfloat162float(h);
}

// ---------------- Kernel P: pack adj bitmask + split W hi/lo (no fences, no counters)
#define PACK_BLOCKS (NN * NN / 256)          // 16384
#define WSPL_BLOCKS (DD * CC / 256)          // 64
__global__ __launch_bounds__(256) void prep_kernel(
    const int* __restrict__ adj, unsigned int* __restrict__ padj,
    const float* __restrict__ W,
    unsigned short* __restrict__ Whi, unsigned short* __restrict__ Wlo)
{
    const int bx  = blockIdx.x;
    const int tid = threadIdx.x;
    if (bx < PACK_BLOCKS) {
        const int idx  = bx * 256 + tid;
        const int i    = idx >> 11;
        const int j    = idx & 2047;
        const int lane = tid & 63;
        int ad = adj[(size_t)i * NN + j];
        unsigned long long m = __ballot(ad > 0);
        if (lane == 0)  padj[i * 64 + (j >> 5)] = (unsigned int)m;
        if (lane == 32) padj[i * 64 + (j >> 5)] = (unsigned int)(m >> 32);
    } else {
        const int g = (bx - PACK_BLOCKS) * 256 + tid;
        float w = W[g];
        unsigned short h = f2bf(w);
        Whi[g] = h;
        Wlo[g] = f2bf(w - bf2f(h));
    }
}

// ---------------- Kernel A: Wh = x @ W^T via compensated MFMA.
// Writes WhbT bf16 [b][d][n], f1 (raw), E2=exp(f2), G2=exp(0.2 f2).
__global__ __launch_bounds__(256) void wh_kernel(
    const float* __restrict__ x,
    const unsigned short* __restrict__ Whi, const unsigned short* __restrict__ Wlo,
    const float* __restrict__ a,
    unsigned short* __restrict__ WhbT,
    float* __restrict__ f1, float* __restrict__ E2g, float* __restrict__ G2g)
{
    const int tid  = threadIdx.x;
    const int b    = blockIdx.y;
    const int n0   = blockIdx.x * 64;
    const int w    = tid >> 6;
    const int lane = tid & 63;
    const int fr   = lane & 15, fk = lane >> 4;
    const int n    = n0 + w * 16 + fr;

    short8 bh[4], bl[4];
    const float* xrow = &x[((size_t)(b * NN) + n) * CC];
    #pragma unroll
    for (int ks = 0; ks < 4; ++ks) {
        float xv[8];
        *(float4*)&xv[0] = *(const float4*)&xrow[(ks * 4 + fk) * 8];
        *(float4*)&xv[4] = *(const float4*)&xrow[(ks * 4 + fk) * 8 + 4];
        #pragma unroll
        for (int e = 0; e < 8; ++e) {
            unsigned short h = f2bf(xv[e]);
            bh[ks][e] = (short)h;
            bl[ks][e] = (short)f2bf(xv[e] - bf2f(h));
        }
    }

    f32x4 acc[8];
    #pragma unroll
    for (int dt = 0; dt < 8; ++dt) acc[dt] = (f32x4){0.f, 0.f, 0.f, 0.f};

    #pragma unroll
    for (int dt = 0; dt < 8; ++dt) {
        #pragma unroll
        for (int ks = 0; ks < 4; ++ks) {
            const int off = (dt * 16 + fr) * CC + (ks * 4 + fk) * 8;
            short8 aH = *(const short8*)&Whi[off];
            short8 aL = *(const short8*)&Wlo[off];
            acc[dt] = __builtin_amdgcn_mfma_f32_16x16x32_bf16(aH, bh[ks], acc[dt], 0, 0, 0);
            acc[dt] = __builtin_amdgcn_mfma_f32_16x16x32_bf16(aH, bl[ks], acc[dt], 0, 0, 0);
            acc[dt] = __builtin_amdgcn_mfma_f32_16x16x32_bf16(aL, bh[ks], acc[dt], 0, 0, 0);
        }
    }

    float p1 = 0.f, p2 = 0.f;
    #pragma unroll
    for (int dt = 0; dt < 8; ++dt) {
        #pragma unroll
        for (int r = 0; r < 4; ++r) {
            const int d = dt * 16 + fk * 4 + r;
            p1 += acc[dt][r] * a[d];
            p2 += acc[dt][r] * a[DD + d];
        }
    }
    p1 += __shfl_xor(p1, 16); p1 += __shfl_xor(p1, 32);
    p2 += __shfl_xor(p2, 16); p2 += __shfl_xor(p2, 32);
    if (fk == 0) {
        f1[b * NN + n]  = p1;
        E2g[b * NN + n] = __expf(p2);
        G2g[b * NN + n] = __expf(0.2f * p2);
    }

    #pragma unroll
    for (int dt = 0; dt < 8; ++dt) {
        #pragma unroll
        for (int r = 0; r < 4; ++r) {
            const int d = dt * 16 + fk * 4 + r;
            WhbT[((size_t)(b * 128 + d)) * NN + n] = f2bf(acc[dt][r]);
        }
    }
}

// ---------------- Kernel C: MFMA attention, 64 i-rows x 128 d, 8 waves.
// P weight = max(E1*E2, G1*G2) == exp(leaky_relu(f1+f2)) (exact identity).
template<int S, bool DIRECT>
__global__ __launch_bounds__(512) void gat_kernel(
    const unsigned short* __restrict__ WhbT,   // [b][128 d][2048 n] bf16
    const unsigned int* __restrict__ padj,     // [2048][64] bitmask
    const float* __restrict__ f1,
    const float* __restrict__ E2g, const float* __restrict__ G2g,
    float* __restrict__ out,
    float* __restrict__ pPV, float* __restrict__ pS)
{
    constexpr int JS = NN / S;
    constexpr int NC = JS / 64;
    __shared__ __align__(16) unsigned short Bs[128 * 64];  // 16 KB
    __shared__ __align__(16) unsigned short Ps[64 * 64];   // 8 KB
    __shared__ float E2s[JS];
    __shared__ float G2s[JS];
    __shared__ float Srow[64];
    __shared__ float Sred[64];

    const int tid   = threadIdx.x;
    const int i0    = blockIdx.x * 64;
    const int split = blockIdx.y;
    const int b     = blockIdx.z;
    const int jBeg  = split * JS;

    #pragma unroll
    for (int k = 0; k < JS / 512; ++k) {
        E2s[tid + 512 * k] = E2g[b * NN + jBeg + tid + 512 * k];
        G2s[tid + 512 * k] = G2g[b * NN + jBeg + tid + 512 * k];
    }

    // P role: row = tid>>3 (64 rows), 8 j-elems at pjb*8
    const int prow = tid >> 3;
    const int pjb  = tid & 7;
    const float f1r = f1[b * NN + i0 + prow];
    const float E1r = __expf(f1r);
    const float G1r = __expf(0.2f * f1r);
    const int psw = ((pjb ^ (prow & 7)) << 3);
    const unsigned int* padjRow = padj + (size_t)(i0 + prow) * 64 + (jBeg >> 5);

    // MFMA role: wave (wr,wc) in 2x4
    const int w    = tid >> 6;
    const int wr   = w >> 2, wc = w & 3;
    const int lane = tid & 63;
    const int fr   = lane & 15;
    const int fk   = lane >> 4;
    f32x4 acc00 = {0.f,0.f,0.f,0.f}, acc01 = {0.f,0.f,0.f,0.f};
    f32x4 acc10 = {0.f,0.f,0.f,0.f}, acc11 = {0.f,0.f,0.f,0.f};
    float s_part = 0.f;

    // B staging: 1024 x 16B loads, 2 per thread
    const size_t wbase = (size_t)b * 128 * NN;
    const int g0 = tid,       gd0 = g0 >> 3, gj0 = (g0 & 7) * 8;
    const int g1 = tid + 512, gd1 = g1 >> 3, gj1 = (g1 & 7) * 8;
    const int sw0 = gd0 * 64 + ((((g0) & 7) ^ (gd0 & 7)) << 3);
    const int sw1 = gd1 * 64 + ((((g1) & 7) ^ (gd1 & 7)) << 3);

    // prefetch chunk 0
    uint4 br0 = *(const uint4*)&WhbT[wbase + (size_t)gd0 * NN + jBeg + gj0];
    uint4 br1 = *(const uint4*)&WhbT[wbase + (size_t)gd1 * NN + jBeg + gj1];
    unsigned int pw = padjRow[pjb >> 2];

    __syncthreads();   // E2s/G2s ready

    for (int c = 0; c < NC; ++c) {
        // (B) P chunk: w = max(E1*E2, G1*G2), masked by bit
        float4 eA = *(const float4*)&E2s[c * 64 + pjb * 8];
        float4 eB = *(const float4*)&E2s[c * 64 + pjb * 8 + 4];
        float4 gA = *(const float4*)&G2s[c * 64 + pjb * 8];
        float4 gB = *(const float4*)&G2s[c * 64 + pjb * 8 + 4];
        float ev[8], gv[8];
        *(float4*)&ev[0] = eA; *(float4*)&ev[4] = eB;
        *(float4*)&gv[0] = gA; *(float4*)&gv[4] = gB;
        unsigned int pbits = (pw >> ((pjb & 3) << 3)) & 0xffu;
        unsigned short pks[8];
        float ssum = 0.f;
        #pragma unroll
        for (int e = 0; e < 8; ++e) {
            float m  = E1r * ev[e];
            float g  = G1r * gv[e];
            float wv = fmaxf(m, g);
            wv = ((pbits >> e) & 1u) ? wv : 0.f;
            unsigned short bw = f2bf(wv);
            pks[e] = bw;
            ssum += bf2f(bw);
        }
        s_part += ssum;

        if (c > 0) __syncthreads();   // prev MFMA done reading LDS
        // (C) LDS writes
        *(uint4*)&Bs[sw0] = br0;
        *(uint4*)&Bs[sw1] = br1;
        {
            uint4 pv;
            pv.x = (unsigned int)pks[0] | ((unsigned int)pks[1] << 16);
            pv.y = (unsigned int)pks[2] | ((unsigned int)pks[3] << 16);
            pv.z = (unsigned int)pks[4] | ((unsigned int)pks[5] << 16);
            pv.w = (unsigned int)pks[6] | ((unsigned int)pks[7] << 16);
            *(uint4*)&Ps[prow * 64 + psw] = pv;
        }
        // (A) prefetch next chunk
        if (c + 1 < NC) {
            const int j0n = jBeg + (c + 1) * 64;
            br0 = *(const uint4*)&WhbT[wbase + (size_t)gd0 * NN + j0n + gj0];
            br1 = *(const uint4*)&WhbT[wbase + (size_t)gd1 * NN + j0n + gj1];
            pw  = padjRow[(c + 1) * 2 + (pjb >> 2)];
        }
        __syncthreads();   // tiles ready
        // (D) MFMA
        __builtin_amdgcn_s_setprio(1);
        #pragma unroll
        for (int ks = 0; ks < 2; ++ks) {
            const int jbl = ks * 4 + fk;
            const int sb  = ((jbl ^ (fr & 7)) << 3);
            short8 aF0 = *(const short8*)&Ps[(wr * 32 + fr) * 64 + sb];
            short8 aF1 = *(const short8*)&Ps[(wr * 32 + 16 + fr) * 64 + sb];
            short8 bF0 = *(const short8*)&Bs[(wc * 32 + fr) * 64 + sb];
            short8 bF1 = *(const short8*)&Bs[(wc * 32 + 16 + fr) * 64 + sb];
            acc00 = __builtin_amdgcn_mfma_f32_16x16x32_bf16(aF0, bF0, acc00, 0, 0, 0);
            acc01 = __builtin_amdgcn_mfma_f32_16x16x32_bf16(aF0, bF1, acc01, 0, 0, 0);
            acc10 = __builtin_amdgcn_mfma_f32_16x16x32_bf16(aF1, bF0, acc10, 0, 0, 0);
            acc11 = __builtin_amdgcn_mfma_f32_16x16x32_bf16(aF1, bF1, acc11, 0, 0, 0);
        }
        __builtin_amdgcn_s_setprio(0);
    }

    // row-sum: 8 threads per row
    {
        float v = s_part;
        v += __shfl_xor(v, 1); v += __shfl_xor(v, 2); v += __shfl_xor(v, 4);
        if (pjb == 0) Srow[prow] = v;
    }
    __syncthreads();
    if (tid < 64) {
        float st = Srow[tid];
        if (DIRECT) Sred[tid] = 1.0f / st;
        else        pS[(size_t)(b * S + split) * NN + i0 + tid] = st;
    }
    __syncthreads();

    #pragma unroll
    for (int it = 0; it < 2; ++it) {
        #pragma unroll
        for (int dt = 0; dt < 2; ++dt) {
            f32x4 av = (it == 0) ? (dt == 0 ? acc00 : acc01)
                                 : (dt == 0 ? acc10 : acc11);
            #pragma unroll
            for (int r = 0; r < 4; ++r) {
                int i = wr * 32 + it * 16 + fk * 4 + r;
                int d = wc * 32 + dt * 16 + fr;
                if (DIRECT) {
                    float hv = av[r] * Sred[i];
                    hv = (hv > 0.f) ? hv : expm1f(hv);
                    out[((size_t)(b * NN) + i0 + i) * DD + d] = hv;
                } else {
                    pPV[((size_t)(b * S + split) * NN + i0 + i) * DD + d] = av[r];
                }
            }
        }
    }
}

// ---------------- Kernel D: combine splits, normalize, elu
template<int S>
__global__ __launch_bounds__(256) void reduce_kernel(
    const float* __restrict__ pPV, const float* __restrict__ pS,
    float* __restrict__ out)
{
    const int idx = blockIdx.x * 256 + threadIdx.x;
    const int bi = idx >> 5;
    const int d4 = (idx & 31) * 4;
    const int b  = bi >> 11;
    const int i  = bi & 2047;
    float4 sum = make_float4(0.f, 0.f, 0.f, 0.f);
    float ssum = 0.f;
    #pragma unroll
    for (int s = 0; s < S; ++s) {
        size_t base = (size_t)(b * S + s) * NN + i;
        float4 v = *(const float4*)&pPV[base * DD + d4];
        sum.x += v.x; sum.y += v.y; sum.z += v.z; sum.w += v.w;
        ssum  += pS[base];
    }
    float inv = 1.0f / ssum;
    float4 h;
    h.x = sum.x * inv; h.y = sum.y * inv; h.z = sum.z * inv; h.w = sum.w * inv;
    h.x = (h.x > 0.f) ? h.x : expm1f(h.x);
    h.y = (h.y > 0.f) ? h.y : expm1f(h.y);
    h.z = (h.z > 0.f) ? h.z : expm1f(h.z);
    h.w = (h.w > 0.f) ? h.w : expm1f(h.w);
    *(float4*)&out[(size_t)bi * DD + d4] = h;
}

extern "C" void kernel_launch(void* const* d_in, const int* in_sizes, int n_in,
                              void* d_out, int out_size, void* d_ws, size_t ws_size,
                              hipStream_t stream) {
    const float* x   = (const float*)d_in[0];
    const int*   adj = (const int*)d_in[1];
    const float* W   = (const float*)d_in[2];
    const float* a   = (const float*)d_in[3];
    float* out = (float*)d_out;

    char* p = (char*)d_ws;
    unsigned short* WhbT = (unsigned short*)p; p += (size_t)BB * NN * DD * 2;  // 4 MB
    float* f1  = (float*)p; p += (size_t)BB * NN * 4;
    float* E2g = (float*)p; p += (size_t)BB * NN * 4;
    float* G2g = (float*)p; p += (size_t)BB * NN * 4;
    unsigned short* Whi = (unsigned short*)p; p += (size_t)DD * CC * 2;
    unsigned short* Wlo = (unsigned short*)p; p += (size_t)DD * CC * 2;
    unsigned int* padj  = (unsigned int*)p;   p += (size_t)NN * 64 * 4;        // 512 KB
    float* pPV = (float*)p;

    const size_t base_bytes = (size_t)(p - (char*)d_ws);
    const size_t per_split  = (size_t)BB * NN * DD * 4 + (size_t)BB * NN * 4;

    prep_kernel<<<PACK_BLOCKS + WSPL_BLOCKS, 256, 0, stream>>>(adj, padj, W, Whi, Wlo);
    wh_kernel<<<dim3(NN / 64, BB), 256, 0, stream>>>(x, Whi, Wlo, a, WhbT, f1, E2g, G2g);

    if (ws_size >= base_bytes + 2 * per_split) {
        constexpr int S = 2;
        float* pS = pPV + (size_t)S * BB * NN * DD;
        gat_kernel<S, false><<<dim3(NN / 64, S, BB), 512, 0, stream>>>(
            WhbT, padj, f1, E2g, G2g, out, pPV, pS);
        reduce_kernel<S><<<BB * NN * DD / 4 / 256, 256, 0, stream>>>(pPV, pS, out);
    } else {
        gat_kernel<1, true><<<dim3(NN / 64, 1, BB), 512, 0, stream>>>(
            WhbT, padj, f1, E2g, G2g, out, nullptr, nullptr);
    }
}